// Round 4
// baseline (237.476 us; speedup 1.0000x reference)
//
#include <hip/hip_runtime.h>
#include <stdint.h>

// WindowWarp: B=256, T=2048, C=64, WINDOW_RATIO=0.1, SCALES={0.5,2.0}
// WARP_SIZE = ceil(0.1*2048) = 205
// L_MAX = T - WARP_SIZE + int(WARP_SIZE*2.0) = 1843 + 410 = 2253
constexpr int Bn     = 256;
constexpr int Tn     = 2048;
constexpr int Cn     = 64;
constexpr int WARPSZ = 205;
constexpr int LMAX   = 2253;

constexpr int TB = 32;   // t-rows per block
constexpr int NR = 72;   // staged source rows per block (worst-case need ~66:
                         // scale 0.5 -> ds/dt = 2.0198*0.9497 = 1.92/t * 31 t
                         // + j1 slack + i1 slack + floor slack)

typedef float f32x4 __attribute__((ext_vector_type(4)));

// Map intermediate index j -> source position s -> (i0, i1, frac) into x rows.
// Arithmetic kept byte-identical to the passing round-3 kernel.
__device__ __forceinline__ void map_j(float jf, float start, float nl, float rdenom,
                                      int& i0, int& i1, float& fr) {
    bool in_win = (jf >= start) && (jf < start + nl);
    bool after  = (jf >= start + nl);
    float s_win   = start + (jf - start) * rdenom;      // rdenom = (WARP-1)/max(nl-1,1)
    float s_after = jf - nl + (float)WARPSZ;
    float s = in_win ? s_win : (after ? s_after : jf);
    s = fminf(fmaxf(s, 0.0f), (float)(Tn - 1));
    float p0 = floorf(s);
    fr = s - p0;
    i0 = (int)p0;
    i1 = min(i0 + 1, Tn - 1);
}

__global__ __launch_bounds__(256) void window_warp_kernel(
        const float* __restrict__ x,
        const float* __restrict__ scales,
        const int*   __restrict__ starts,
        float*       __restrict__ out) {
    // 18.4 KB of LDS -> 8 blocks/CU * 4 waves = 32 waves/CU (max occupancy).
    __shared__ f32x4 smem[NR * (Cn / 4)];

    // Bijective XCD swizzle: 16384 blocks = 8 XCDs * 2048. Consecutive logical
    // blocks (which share staged source rows) land on the SAME XCD's L2, so
    // the ~2x staging overlap between neighbors dedups in L2 instead of HBM.
    int n    = blockIdx.x;
    int bidx = ((n & 7) << 11) | (n >> 3);
    int b     = bidx >> 6;          // 64 blocks per batch (wave-uniform)
    int t0    = (bidx & 63) << 5;   // first of 32 t-rows
    int tslot = threadIdx.x >> 4;
    int cg    = threadIdx.x & 15;

    float scale = scales[b];
    float start = (float)starts[b];
    float nl    = floorf((float)WARPSZ * scale);        // new_len
    float Lm1   = (float)(Tn - WARPSZ) + nl - 1.0f;     // L - 1
    float rdenom = (float)(WARPSZ - 1) / fmaxf(nl - 1.0f, 1.0f);

    // Block-uniform first source row (index map is monotone in t and j).
    float u0 = ((float)t0 * Lm1) / (float)(Tn - 1);
    u0 = fminf(fmaxf(u0, 0.0f), Lm1);
    int j00 = (int)floorf(u0);
    int r0a, r0b; float fr0;
    map_j((float)j00, start, nl, rdenom, r0a, r0b, fr0);
    int rbase = min(r0a, Tn - NR);  // clamp keeps rows [rbase, rbase+NR) in range

    // --- Stage NR rows (18432 B) direct-to-LDS: no VGPR round trip, deep
    // vmcnt pipeline (5 x 1 KB outstanding per wave) -> staging is BW-bound,
    // not latency-bound like the old VGPR gathers.
    {
        const float* gbase = x + (size_t)b * (Tn * Cn) + rbase * Cn;
        int wave = threadIdx.x >> 6;
        int lane = threadIdx.x & 63;
        float* sm = (float*)smem;
        #pragma unroll
        for (int c = wave; c < (NR * Cn * 4) / 1024; c += 4) {   // 18 chunks
            __builtin_amdgcn_global_load_lds(
                (const __attribute__((address_space(1))) uint32_t*)(gbase + c * 256 + lane * 4),
                (__attribute__((address_space(3))) uint32_t*)(sm + c * 256),
                16, 0, 0);
        }
    }
    __syncthreads();   // compiler drains vmcnt(0) before s_barrier

    // --- Gather from LDS. Each 16-lane quarter-wave reads one contiguous
    // 256 B row per ds_read_b128 phase -> bank-conflict-free.
    int   i00[2], i01[2], i10[2], i11[2];
    float f0[2], f1[2], fu[2];
    #pragma unroll
    for (int k = 0; k < 2; ++k) {
        int t = t0 + tslot + 16 * k;
        float u = ((float)t * Lm1) / (float)(Tn - 1);
        u = fminf(fmaxf(u, 0.0f), Lm1);
        float q0 = floorf(u);
        fu[k] = u - q0;
        int j0 = (int)q0;
        int j1 = min(j0 + 1, LMAX - 1);
        map_j((float)j0, start, nl, rdenom, i00[k], i01[k], f0[k]);
        map_j((float)j1, start, nl, rdenom, i10[k], i11[k], f1[k]);
    }

    f32x4 A0[2], A1[2], B0[2], B1[2];
    #pragma unroll
    for (int k = 0; k < 2; ++k) {
        A0[k] = smem[(i00[k] - rbase) * 16 + cg];
        A1[k] = smem[(i01[k] - rbase) * 16 + cg];
        B0[k] = smem[(i10[k] - rbase) * 16 + cg];
        B1[k] = smem[(i11[k] - rbase) * 16 + cg];
    }

    f32x4* outb = (f32x4*)(out + (size_t)b * (Tn * Cn));
    #pragma unroll
    for (int k = 0; k < 2; ++k) {
        int t = t0 + tslot + 16 * k;
        float g0 = 1.0f - f0[k], g1 = 1.0f - f1[k], gu = 1.0f - fu[k];
        f32x4 v0 = A0[k] * g0 + A1[k] * f0[k];
        f32x4 v1 = B0[k] * g1 + B1[k] * f1[k];
        f32x4 r  = v0 * gu + v1 * fu[k];
        // Write-once stream: nontemporal keeps stores from evicting staged x.
        __builtin_nontemporal_store(r, &outb[t * 16 + cg]);
    }
}

extern "C" void kernel_launch(void* const* d_in, const int* in_sizes, int n_in,
                              void* d_out, int out_size, void* d_ws, size_t ws_size,
                              hipStream_t stream) {
    const float* x      = (const float*)d_in[0];
    const float* scales = (const float*)d_in[1];
    const int*   starts = (const int*)d_in[2];
    float* out = (float*)d_out;

    // One block per 32 t-rows: B*T/32 = 16384 blocks (= 8 XCDs * 2048).
    int blocks = Bn * Tn / TB;
    window_warp_kernel<<<blocks, 256, 0, stream>>>(x, scales, starts, out);
}